// Round 1
// baseline (3096.498 us; speedup 1.0000x reference)
//
#include <hip/hip_runtime.h>
#include <math.h>

#define B_  32
#define S_  1024
#define D_  256
#define DS_ 64
#define M_  3
#define MD_ 192   // M*DS

// ---------------------------------------------------------------------------
// Kernel 1: xp[b][t][m*64+d] = Xb[m][d] + sum_k XW[m][d][k] * x_m[b][t][k]
// grid (8, 32, 3) = (t-chunk of 128, b, m); block 256 = 4 K-quarters x 64 d
// ---------------------------------------------------------------------------
__global__ __launch_bounds__(256, 2)
void k1_xproj(const float* __restrict__ xa, const float* __restrict__ xv,
              const float* __restrict__ xl, const float* __restrict__ XW,
              const float* __restrict__ Xb, float* __restrict__ xp)
{
    const int m  = blockIdx.z;
    const int b  = blockIdx.y;
    const int t0 = blockIdx.x * 128;
    const float* __restrict__ xm = (m == 0) ? xa : ((m == 1) ? xv : xl);
    const int tid = threadIdx.x;
    const int q = tid >> 6;    // K quarter 0..3
    const int d = tid & 63;

    __shared__ __align__(16) float xs[4][256];
    __shared__ float part[4][4][64];   // [tt][q][d]

    // register-resident quarter-row of XW[m][d][q*64 .. q*64+63]
    float w[64];
    {
        const float4* src = reinterpret_cast<const float4*>(XW + ((m * 64 + d) * 256 + q * 64));
        #pragma unroll
        for (int e4 = 0; e4 < 16; ++e4) {
            float4 v = src[e4];
            w[e4 * 4 + 0] = v.x; w[e4 * 4 + 1] = v.y;
            w[e4 * 4 + 2] = v.z; w[e4 * 4 + 3] = v.w;
        }
    }
    const float xbv = Xb[m * 64 + d];

    for (int g = 0; g < 32; ++g) {
        const int tb = t0 + g * 4;
        // stage 4 rows of x (coalesced)
        {
            const float* src = xm + ((size_t)b * S_ + tb) * D_;
            #pragma unroll
            for (int r = 0; r < 4; ++r)
                xs[r][tid] = src[r * 256 + tid];
        }
        __syncthreads();
        // partial dots (x from LDS broadcast, weights from registers)
        #pragma unroll
        for (int tt = 0; tt < 4; ++tt) {
            const float4* xq = reinterpret_cast<const float4*>(&xs[tt][q * 64]);
            float a0 = 0.f, a1 = 0.f, a2 = 0.f, a3 = 0.f;
            #pragma unroll
            for (int e4 = 0; e4 < 16; ++e4) {
                float4 hv = xq[e4];
                a0 += w[e4 * 4 + 0] * hv.x; a1 += w[e4 * 4 + 1] * hv.y;
                a2 += w[e4 * 4 + 2] * hv.z; a3 += w[e4 * 4 + 3] * hv.w;
            }
            part[tt][q][d] = (a0 + a1) + (a2 + a3);
        }
        __syncthreads();
        // finalize: thread (tt=q, d) sums the 4 quarters
        {
            const int tt = q;
            float ssum = part[tt][0][d] + part[tt][1][d] + part[tt][2][d] + part[tt][3][d] + xbv;
            xp[((size_t)b * S_ + tb + tt) * MD_ + m * 64 + d] = ssum;
        }
        // no extra barrier needed: next g's part-writes happen only after its
        // post-stage barrier, which all threads (done reading part) must reach
    }
}

// ---------------------------------------------------------------------------
// Kernel 2: the sequential recurrence. grid 32 (one block per b), block 256.
// threads 0..191  ("su"): output (m = tid/64, d = tid%64); register weights =
//      concat over s of (s==m ? HW[m][d][:] : CW[m][s][d][:])   (192 floats)
// threads 192..255 ("gate"): lane j holds W1 row j (192 floats); computes
//      z=tanh(W1@hflat+b1), raw=W2@z+b2 (lanes j<9, W2 from LDS), softmax
//      (lanes j<3) -> attn in LDS. In-wave LDS write->read ordering, no
//      barrier inside the gate chain.
// 2 __syncthreads per step.
// ---------------------------------------------------------------------------
__global__ __launch_bounds__(256, 1)
void k2_recur(const float* __restrict__ xp, float* __restrict__ hbuf,
              const float* __restrict__ HW, const float* __restrict__ Hb,
              const float* __restrict__ CW, const float* __restrict__ W1,
              const float* __restrict__ b1, const float* __restrict__ W2,
              const float* __restrict__ b2)
{
    const int b   = blockIdx.x;
    const int tid = threadIdx.x;
    const bool su = (tid < MD_);
    const int d   = tid & 63;
    const int j   = tid - MD_;   // gate lane (valid when !su)

    __shared__ __align__(16) float hsh[MD_];
    __shared__ __align__(16) float zsh[64];
    __shared__ __align__(16) float w2s[9 * 68];   // padded rows, 16B-aligned
    __shared__ float rawsh[12];
    __shared__ float attnsh[12];

    for (int idx = tid; idx < 9 * 64; idx += 256)
        w2s[(idx / 64) * 68 + (idx & 63)] = W2[idx];
    if (su) hsh[tid] = 0.f;

    // -------- register weight preload --------
    float wk[3][64];
    if (su) {
        const int m = tid / 64;
        #pragma unroll
        for (int s = 0; s < 3; ++s) {
            const float* base = (s == m) ? (HW + (m * 64 + d) * 64)
                                         : (CW + (((m * 3 + s) * 64) + d) * 64);
            const float4* src = reinterpret_cast<const float4*>(base);
            #pragma unroll
            for (int e4 = 0; e4 < 16; ++e4) {
                float4 v = src[e4];
                wk[s][e4 * 4 + 0] = v.x; wk[s][e4 * 4 + 1] = v.y;
                wk[s][e4 * 4 + 2] = v.z; wk[s][e4 * 4 + 3] = v.w;
            }
        }
    } else {
        const float4* src = reinterpret_cast<const float4*>(W1 + j * 192);
        #pragma unroll
        for (int s = 0; s < 3; ++s)
            #pragma unroll
            for (int e4 = 0; e4 < 16; ++e4) {
                float4 v = src[s * 16 + e4];
                wk[s][e4 * 4 + 0] = v.x; wk[s][e4 * 4 + 1] = v.y;
                wk[s][e4 * 4 + 2] = v.z; wk[s][e4 * 4 + 3] = v.w;
            }
    }

    float biasv;
    if (su) biasv = Hb[tid];            // Hb[m*64+d] == Hb[tid] for tid<192
    else    biasv = b1[j];
    float b2v = 0.f;
    if (!su && j < 9) b2v = b2[j];

    const int m = su ? (tid / 64) : 0;

    // prefetch xp for t=0
    float xnext = su ? xp[(size_t)b * S_ * MD_ + tid] : 0.f;

    __syncthreads();

    for (int t = 0; t < S_; ++t) {
        const float xv = xnext;
        if (su && (t + 1 < S_))
            xnext = xp[((size_t)b * S_ + t + 1) * MD_ + tid];

        // ---- segment dots over h (LDS broadcast) with register weights ----
        float cp0, cp1, cp2;
        {
            const float4* h4 = reinterpret_cast<const float4*>(hsh);
            #pragma unroll
            for (int s = 0; s < 3; ++s) {
                float a0 = 0.f, a1 = 0.f, a2 = 0.f, a3 = 0.f;
                #pragma unroll
                for (int e4 = 0; e4 < 16; ++e4) {
                    float4 hv = h4[s * 16 + e4];
                    a0 += wk[s][e4 * 4 + 0] * hv.x; a1 += wk[s][e4 * 4 + 1] * hv.y;
                    a2 += wk[s][e4 * 4 + 2] * hv.z; a3 += wk[s][e4 * 4 + 3] * hv.w;
                }
                float r = (a0 + a1) + (a2 + a3);
                if (s == 0) cp0 = r; else if (s == 1) cp1 = r; else cp2 = r;
            }
        }

        if (!su) {
            // gate chain: z -> raw -> softmax(attn). Single wave, in-order.
            float z = tanhf(biasv + cp0 + cp1 + cp2);
            zsh[j] = z;
            if (j < 9) {
                const float4* z4 = reinterpret_cast<const float4*>(zsh);
                const float4* w4 = reinterpret_cast<const float4*>(&w2s[j * 68]);
                float a0 = 0.f, a1 = 0.f, a2 = 0.f, a3 = 0.f;
                #pragma unroll
                for (int q4 = 0; q4 < 16; ++q4) {
                    float4 zz = z4[q4]; float4 ww = w4[q4];
                    a0 += zz.x * ww.x; a1 += zz.y * ww.y;
                    a2 += zz.z * ww.z; a3 += zz.w * ww.w;
                }
                rawsh[j] = b2v + (a0 + a1) + (a2 + a3);
            }
            if (j < 3) {
                float r0 = rawsh[j * 3 + 0], r1 = rawsh[j * 3 + 1], r2 = rawsh[j * 3 + 2];
                float mx = fmaxf(r0, fmaxf(r1, r2));
                float e0 = expf(r0 - mx), e1 = expf(r1 - mx), e2 = expf(r2 - mx);
                float inv = 1.f / (e0 + e1 + e2);
                attnsh[j * 3 + 0] = e0 * inv;
                attnsh[j * 3 + 1] = e1 * inv;
                attnsh[j * 3 + 2] = e2 * inv;
            }
        }
        __syncthreads();   // attn ready; all h reads done

        if (su) {
            float w0 = (m == 0) ? 1.f : attnsh[m * 3 + 0];
            float w1v = (m == 1) ? 1.f : attnsh[m * 3 + 1];
            float w2v = (m == 2) ? 1.f : attnsh[m * 3 + 2];
            float suv = xv + biasv + w0 * cp0 + w1v * cp1 + w2v * cp2;
            float hn = suv / (1.f + expf(-suv));     // silu
            hsh[tid] = hn;
            hbuf[((size_t)b * S_ + t) * MD_ + tid] = hn;
        }
        __syncthreads();   // h_new visible for next step
    }
}

// ---------------------------------------------------------------------------
// Kernel 3: out[m][b][t][k] = LN_k( Ob[m][k] + OW[m][k]@h[b][t][m] + x_m[b][t][k] )
// grid (8, 32, 3); block 256 (one thread per k). OW row in registers.
// ---------------------------------------------------------------------------
__global__ __launch_bounds__(256, 2)
void k3_out(const float* __restrict__ xa, const float* __restrict__ xv,
            const float* __restrict__ xl, const float* __restrict__ hbuf,
            const float* __restrict__ OW, const float* __restrict__ Ob,
            const float* __restrict__ lng, const float* __restrict__ lnb,
            float* __restrict__ out)
{
    const int m  = blockIdx.z;
    const int b  = blockIdx.y;
    const int t0 = blockIdx.x * 128;
    const float* __restrict__ xm = (m == 0) ? xa : ((m == 1) ? xv : xl);
    const int k    = threadIdx.x;
    const int wv   = k >> 6;
    const int lane = k & 63;

    __shared__ __align__(16) float hs[4 * 64];
    __shared__ float psum[16], qsum[16];   // [wave*4 + tt]

    float ow[64];
    {
        const float4* src = reinterpret_cast<const float4*>(OW + (m * D_ + k) * DS_);
        #pragma unroll
        for (int e4 = 0; e4 < 16; ++e4) {
            float4 v = src[e4];
            ow[e4 * 4 + 0] = v.x; ow[e4 * 4 + 1] = v.y;
            ow[e4 * 4 + 2] = v.z; ow[e4 * 4 + 3] = v.w;
        }
    }
    const float obv = Ob[m * D_ + k];
    const float gv  = lng[m * D_ + k];
    const float bv  = lnb[m * D_ + k];

    for (int g = 0; g < 32; ++g) {
        const int tb = t0 + g * 4;
        // stage 4 h rows (coalesced-ish)
        hs[k] = hbuf[((size_t)b * S_ + tb + (k >> 6)) * MD_ + m * 64 + (k & 63)];
        __syncthreads();

        float v[4];
        #pragma unroll
        for (int tt = 0; tt < 4; ++tt) {
            const float4* h4 = reinterpret_cast<const float4*>(&hs[tt * 64]);
            float a0 = 0.f, a1 = 0.f, a2 = 0.f, a3 = 0.f;
            #pragma unroll
            for (int e4 = 0; e4 < 16; ++e4) {
                float4 hv = h4[e4];
                a0 += ow[e4 * 4 + 0] * hv.x; a1 += ow[e4 * 4 + 1] * hv.y;
                a2 += ow[e4 * 4 + 2] * hv.z; a3 += ow[e4 * 4 + 3] * hv.w;
            }
            float y = obv + (a0 + a1) + (a2 + a3);
            v[tt] = y + xm[((size_t)b * S_ + tb + tt) * D_ + k];
        }

        // block reduction: sum & sumsq per tt over 256 threads
        float s[4], q[4];
        #pragma unroll
        for (int tt = 0; tt < 4; ++tt) { s[tt] = v[tt]; q[tt] = v[tt] * v[tt]; }
        #pragma unroll
        for (int off = 32; off >= 1; off >>= 1) {
            #pragma unroll
            for (int tt = 0; tt < 4; ++tt) {
                s[tt] += __shfl_down(s[tt], off);
                q[tt] += __shfl_down(q[tt], off);
            }
        }
        if (lane == 0) {
            #pragma unroll
            for (int tt = 0; tt < 4; ++tt) { psum[wv * 4 + tt] = s[tt]; qsum[wv * 4 + tt] = q[tt]; }
        }
        __syncthreads();

        #pragma unroll
        for (int tt = 0; tt < 4; ++tt) {
            float ss = psum[0 + tt] + psum[4 + tt] + psum[8 + tt] + psum[12 + tt];
            float qq = qsum[0 + tt] + qsum[4 + tt] + qsum[8 + tt] + qsum[12 + tt];
            float mu  = ss * (1.f / 256.f);
            float var = qq * (1.f / 256.f) - mu * mu;
            float rs  = rsqrtf(var + 1e-5f);
            out[(size_t)m * ((size_t)B_ * S_ * D_) + ((size_t)b * S_ + tb + tt) * D_ + k]
                = (v[tt] - mu) * rs * gv + bv;
        }
        // next g's hs/psum writes are fenced by its post-stage barrier
    }
}

extern "C" void kernel_launch(void* const* d_in, const int* in_sizes, int n_in,
                              void* d_out, int out_size, void* d_ws, size_t ws_size,
                              hipStream_t stream)
{
    const float* xa  = (const float*)d_in[0];
    const float* xv  = (const float*)d_in[1];
    const float* xl  = (const float*)d_in[2];
    const float* XW  = (const float*)d_in[3];
    const float* Xb  = (const float*)d_in[4];
    const float* HW  = (const float*)d_in[5];
    const float* Hb  = (const float*)d_in[6];
    const float* OW  = (const float*)d_in[7];
    const float* Ob  = (const float*)d_in[8];
    const float* CW  = (const float*)d_in[9];
    const float* W1  = (const float*)d_in[10];
    const float* b1  = (const float*)d_in[11];
    const float* W2  = (const float*)d_in[12];
    const float* b2  = (const float*)d_in[13];
    const float* lng = (const float*)d_in[14];
    const float* lnb = (const float*)d_in[15];
    float* out = (float*)d_out;

    float* xp = (float*)d_ws;                          // [B][S][192]
    float* hb = xp + (size_t)B_ * S_ * MD_;            // [B][S][192]

    k1_xproj<<<dim3(8, 32, 3), 256, 0, stream>>>(xa, xv, xl, XW, Xb, xp);
    k2_recur<<<dim3(32), 256, 0, stream>>>(xp, hb, HW, Hb, CW, W1, b1, W2, b2);
    k3_out  <<<dim3(8, 32, 3), 256, 0, stream>>>(xa, xv, xl, hb, OW, Ob, lng, lnb, out);
}